// Round 4
// baseline (771.114 us; speedup 1.0000x reference)
//
#include <hip/hip_runtime.h>
#include <math.h>

#define P_TOTAL 65536
#define NRAYS   1024
#define NSAMP   64
#define NV      6890
#define NF      96
#define NW      128
#define NCHUNK  4
#define LSTRIDE 129   // 128+1 pad: bank = (tid + k) % 32 -> 2-way alias (free)

// ---------------- K1: per-ray min/max normalize, pack (x,y,z,p2) ----------------
__global__ __launch_bounds__(64) void k_norm(const float* __restrict__ pts,
                                             float4* __restrict__ out) {
    int ray = blockIdx.x;
    int s   = threadIdx.x;
    const float* p = pts + (size_t)(ray * NSAMP + s) * 3;
    float x = p[0], y = p[1], z = p[2];
    float mnx = x, mxx = x, mny = y, mxy = y, mnz = z, mxz = z;
#pragma unroll
    for (int off = 32; off > 0; off >>= 1) {
        mnx = fminf(mnx, __shfl_xor(mnx, off));
        mxx = fmaxf(mxx, __shfl_xor(mxx, off));
        mny = fminf(mny, __shfl_xor(mny, off));
        mxy = fmaxf(mxy, __shfl_xor(mxy, off));
        mnz = fminf(mnz, __shfl_xor(mnz, off));
        mxz = fmaxf(mxz, __shfl_xor(mxz, off));
    }
    // (p - mn) / (mx - mn), per-op rounded exactly like numpy elementwise
    float nx = __fdiv_rn(__fsub_rn(x, mnx), __fsub_rn(mxx, mnx));
    float ny = __fdiv_rn(__fsub_rn(y, mny), __fsub_rn(mxy, mny));
    float nz = __fdiv_rn(__fsub_rn(z, mnz), __fsub_rn(mxz, mnz));
    // p2 = (x*x + y*y) + z*z, each op rounded (numpy sum over len-3 axis)
    float p2 = __fadd_rn(__fadd_rn(__fmul_rn(nx, nx), __fmul_rn(ny, ny)), __fmul_rn(nz, nz));
    out[ray * NSAMP + s] = make_float4(nx, ny, nz, p2);
}

// ---------------- K2: pack vertices as (x,y,z,v2) ----------------
__global__ __launch_bounds__(256) void k_pack(const float* __restrict__ verts,
                                              float4* __restrict__ vv) {
    int v = blockIdx.x * 256 + threadIdx.x;
    if (v < NV) {
        float x = verts[v * 3 + 0], y = verts[v * 3 + 1], z = verts[v * 3 + 2];
        float v2 = __fadd_rn(__fadd_rn(__fmul_rn(x, x), __fmul_rn(y, y)), __fmul_rn(z, z));
        vv[v] = make_float4(x, y, z, v2);
    }
}

// ---------------- K3: brute-force NN, vertex range split 4-ways ----------------
__global__ __launch_bounds__(256) void k_nn(const float4* __restrict__ pts,
                                            const float4* __restrict__ vv,
                                            float* __restrict__ nn_d2,
                                            int* __restrict__ nn_ix) {
    int p     = blockIdx.x * 256 + threadIdx.x;
    int chunk = blockIdx.y;
    int v0 = (chunk * NV) / NCHUNK;
    int v1 = ((chunk + 1) * NV) / NCHUNK;
    float4 pt = pts[p];
    float best = INFINITY;
    int bi = 0;
#pragma unroll 4
    for (int v = v0; v < v1; ++v) {
        float4 vb = vv[v];  // wave-uniform address -> scalar load
        // BLAS-style ascending-k fma dot; fma(a0,b0,0) == rounded product
        float dot = __fmaf_rn(pt.z, vb.z, __fmaf_rn(pt.y, vb.y, __fmul_rn(pt.x, vb.x)));
        // d2 = (p2 - 2*dot) + v2, per-op rounded like numpy elementwise
        float d2 = __fadd_rn(__fsub_rn(pt.w, __fmul_rn(2.0f, dot)), vb.w);
        if (d2 < best) { best = d2; bi = v; }  // strict < keeps FIRST min
    }
    nn_d2[chunk * P_TOTAL + p] = best;
    nn_ix[chunk * P_TOTAL + p] = bi;
}

// ---------------- K4: combine NN + gather + fused 3-layer MLP + blend ----------------
template <int IN>
__device__ __forceinline__ void mlp_layer(const float* __restrict__ row,
                                          const float* __restrict__ W,
                                          const float* __restrict__ b,
                                          float* __restrict__ h) {
#pragma unroll
    for (int c = 0; c < 4; ++c) {
        float acc[32];
#pragma unroll
        for (int j = 0; j < 32; ++j) acc[j] = 0.0f;
        const float* w = W + c * 32;
#pragma unroll 2
        for (int k = 0; k < IN; ++k) {
            float a = row[k];                    // own LDS row, 2-way alias only
            const float* wr = w + (size_t)k * NW; // wave-uniform -> scalar loads
#pragma unroll
            for (int j = 0; j < 32; ++j) acc[j] = __fmaf_rn(a, wr[j], acc[j]);
        }
#pragma unroll
        for (int j = 0; j < 32; ++j)
            h[c * 32 + j] = fmaxf(__fadd_rn(acc[j], b[c * 32 + j]), 0.0f);
    }
}

__global__ __launch_bounds__(64, 1) void k_mlp(
    const float* __restrict__ tri_feats,
    const float* __restrict__ nn_d2, const int* __restrict__ nn_ix,
    const float* __restrict__ W0, const float* __restrict__ b0,
    const float* __restrict__ W1, const float* __restrict__ b1,
    const float* __restrict__ W2, const float* __restrict__ b2,
    const float* __restrict__ W3, const float* __restrict__ b3,
    const float* __restrict__ nerf, const float* __restrict__ bw_in,
    float* __restrict__ out) {
    __shared__ float lds[64 * LSTRIDE];
    int tid = threadIdx.x;
    int p   = blockIdx.x * 64 + tid;

    // combine the 4 NN partials (ascending chunk order, strict < -> first min)
    float bd = nn_d2[p];
    int   bi = nn_ix[p];
#pragma unroll
    for (int c = 1; c < NCHUNK; ++c) {
        float d  = nn_d2[c * P_TOTAL + p];
        int   i2 = nn_ix[c * P_TOTAL + p];
        if (d < bd) { bd = d; bi = i2; }
    }

    // gather this point's feature row into its private LDS row
    const float4* fr = (const float4*)(tri_feats + (size_t)bi * NF);
    float* row = lds + tid * LSTRIDE;
#pragma unroll
    for (int i = 0; i < NF / 4; ++i) {
        float4 v = fr[i];
        row[4 * i + 0] = v.x; row[4 * i + 1] = v.y;
        row[4 * i + 2] = v.z; row[4 * i + 3] = v.w;
    }

    float h[NW];
    mlp_layer<NF>(row, W0, b0, h);   // 96 -> 128, relu
#pragma unroll
    for (int k = 0; k < NW; ++k) row[k] = h[k];
    mlp_layer<NW>(row, W1, b1, h);   // 128 -> 128, relu
#pragma unroll
    for (int k = 0; k < NW; ++k) row[k] = h[k];
    mlp_layer<NW>(row, W2, b2, h);   // 128 -> 128, relu

    // final dot: 128 -> 1 (ascending-k fma chain)
    float acc = 0.0f;
#pragma unroll
    for (int k = 0; k < NW; ++k) acc = __fmaf_rn(h[k], W3[k], acc);
    float dens = __fadd_rn(acc, b3[0]);

    float xw = bw_in[0];
    float bw = 1.0f / (1.0f + expf(-xw));  // sigmoid (stop_gradient = identity fwd)
    float o  = __fadd_rn(__fmul_rn(bw, nerf[p]),
                         __fmul_rn(__fsub_rn(1.0f, bw), dens));
    out[p] = o;
}

extern "C" void kernel_launch(void* const* d_in, const int* in_sizes, int n_in,
                              void* d_out, int out_size, void* d_ws, size_t ws_size,
                              hipStream_t stream) {
    const float* pts   = (const float*)d_in[0];
    const float* verts = (const float*)d_in[1];
    const float* feats = (const float*)d_in[2];
    const float* nerf  = (const float*)d_in[3];
    const float* bw    = (const float*)d_in[4];
    const float* W0 = (const float*)d_in[5];
    const float* b0 = (const float*)d_in[6];
    const float* W1 = (const float*)d_in[7];
    const float* b1 = (const float*)d_in[8];
    const float* W2 = (const float*)d_in[9];
    const float* b2 = (const float*)d_in[10];
    const float* W3 = (const float*)d_in[11];
    const float* b3 = (const float*)d_in[12];

    char* ws = (char*)d_ws;
    float4* pts4  = (float4*)(ws);                              // 1 MB
    float4* vv    = (float4*)(ws + (1 << 20));                  // 110 KB
    float*  nn_d2 = (float*)(ws + (1 << 20) + (128 << 10));     // 1 MB
    int*    nn_ix = (int*)(ws + (2 << 20) + (128 << 10));       // 1 MB

    hipLaunchKernelGGL(k_norm, dim3(NRAYS), dim3(64), 0, stream, pts, pts4);
    hipLaunchKernelGGL(k_pack, dim3((NV + 255) / 256), dim3(256), 0, stream, verts, vv);
    hipLaunchKernelGGL(k_nn, dim3(P_TOTAL / 256, NCHUNK), dim3(256), 0, stream,
                       pts4, vv, nn_d2, nn_ix);
    hipLaunchKernelGGL(k_mlp, dim3(P_TOTAL / 64), dim3(64), 0, stream,
                       feats, nn_d2, nn_ix, W0, b0, W1, b1, W2, b2, W3, b3,
                       nerf, bw, (float*)d_out);
}

// Round 9
// 606.673 us; speedup vs baseline: 1.2711x; 1.2711x over previous
//
#include <hip/hip_runtime.h>
#include <math.h>

#define P_TOTAL 65536
#define NRAYS   1024
#define NSAMP   64
#define NV      6890
#define NF      96
#define NW      128
#define NCHUNK  4
#define LSTRIDE 129   // 128+1 pad: bank = (tid + k) % 32 -> 2-way alias (free)

// ---------------- K1: per-ray min/max normalize, pack (x,y,z,p2) ----------------
__global__ __launch_bounds__(64) void k_norm(const float* __restrict__ pts,
                                             float4* __restrict__ out) {
    int ray = blockIdx.x;
    int s   = threadIdx.x;
    const float* p = pts + (size_t)(ray * NSAMP + s) * 3;
    float x = p[0], y = p[1], z = p[2];
    float mnx = x, mxx = x, mny = y, mxy = y, mnz = z, mxz = z;
#pragma unroll
    for (int off = 32; off > 0; off >>= 1) {
        mnx = fminf(mnx, __shfl_xor(mnx, off));
        mxx = fmaxf(mxx, __shfl_xor(mxx, off));
        mny = fminf(mny, __shfl_xor(mny, off));
        mxy = fmaxf(mxy, __shfl_xor(mxy, off));
        mnz = fminf(mnz, __shfl_xor(mnz, off));
        mxz = fmaxf(mxz, __shfl_xor(mxz, off));
    }
    // (p - mn) / (mx - mn), per-op rounded exactly like numpy elementwise
    float nx = __fdiv_rn(__fsub_rn(x, mnx), __fsub_rn(mxx, mnx));
    float ny = __fdiv_rn(__fsub_rn(y, mny), __fsub_rn(mxy, mny));
    float nz = __fdiv_rn(__fsub_rn(z, mnz), __fsub_rn(mxz, mnz));
    // p2 = (x*x + y*y) + z*z, each op rounded (numpy sum over len-3 axis)
    float p2 = __fadd_rn(__fadd_rn(__fmul_rn(nx, nx), __fmul_rn(ny, ny)), __fmul_rn(nz, nz));
    out[ray * NSAMP + s] = make_float4(nx, ny, nz, p2);
}

// ---------------- K2: pack vertices as (x,y,z,v2) ----------------
__global__ __launch_bounds__(256) void k_pack(const float* __restrict__ verts,
                                              float4* __restrict__ vv) {
    int v = blockIdx.x * 256 + threadIdx.x;
    if (v < NV) {
        float x = verts[v * 3 + 0], y = verts[v * 3 + 1], z = verts[v * 3 + 2];
        float v2 = __fadd_rn(__fadd_rn(__fmul_rn(x, x), __fmul_rn(y, y)), __fmul_rn(z, z));
        vv[v] = make_float4(x, y, z, v2);
    }
}

// ---------------- K3: brute-force NN, vertex range split 4-ways ----------------
__global__ __launch_bounds__(256) void k_nn(const float4* __restrict__ pts,
                                            const float4* __restrict__ vv,
                                            float* __restrict__ nn_d2,
                                            int* __restrict__ nn_ix) {
    int p     = blockIdx.x * 256 + threadIdx.x;
    int chunk = blockIdx.y;
    int v0 = (chunk * NV) / NCHUNK;
    int v1 = ((chunk + 1) * NV) / NCHUNK;
    float4 pt = pts[p];
    float best = INFINITY;
    int bi = 0;
#pragma unroll 4
    for (int v = v0; v < v1; ++v) {
        float4 vb = vv[v];  // wave-uniform address -> scalar load
        // BLAS-style ascending-k fma dot; fma(a0,b0,0) == rounded product
        float dot = __fmaf_rn(pt.z, vb.z, __fmaf_rn(pt.y, vb.y, __fmul_rn(pt.x, vb.x)));
        // d2 = (p2 - 2*dot) + v2, per-op rounded like numpy elementwise
        float d2 = __fadd_rn(__fsub_rn(pt.w, __fmul_rn(2.0f, dot)), vb.w);
        if (d2 < best) { best = d2; bi = v; }  // strict < keeps FIRST min
    }
    nn_d2[chunk * P_TOTAL + p] = best;
    nn_ix[chunk * P_TOTAL + p] = bi;
}

// ---------------- K4: combine NN + gather + fused 3-layer MLP + blend ----------------
// Single k-pass over ALL 128 output columns: per k-step 1 ds_read + 512 B uniform
// weight row + 128 independent FMAs -> ~256 cy of ILP per dependency, latency
// hidden even at 1 wave/SIMD (LDS-capped occupancy). Relu writes back in-place
// to the LDS row AFTER the k-loop (input fully consumed), so acc[128] is the
// only large register array (static indices only -> stays in VGPRs).
template <int IN>
__device__ __forceinline__ void mlp_layer_full(float* __restrict__ row,
                                               const float* __restrict__ W,
                                               const float* __restrict__ b) {
    float acc[NW];
#pragma unroll
    for (int j = 0; j < NW; ++j) acc[j] = 0.0f;
#pragma unroll 2
    for (int k = 0; k < IN; ++k) {
        float a = row[k];                      // own LDS row, 2-way alias only
        const float* wr = W + (size_t)k * NW;  // wave-uniform, 512 B contiguous
#pragma unroll
        for (int j = 0; j < NW; ++j) acc[j] = __fmaf_rn(a, wr[j], acc[j]);
    }
    // h = relu(acc + b), written back over the input row (same order as numpy)
#pragma unroll
    for (int j = 0; j < NW; ++j)
        row[j] = fmaxf(__fadd_rn(acc[j], b[j]), 0.0f);
}

__global__ __launch_bounds__(64, 1) void k_mlp(
    const float* __restrict__ tri_feats,
    const float* __restrict__ nn_d2, const int* __restrict__ nn_ix,
    const float* __restrict__ W0, const float* __restrict__ b0,
    const float* __restrict__ W1, const float* __restrict__ b1,
    const float* __restrict__ W2, const float* __restrict__ b2,
    const float* __restrict__ W3, const float* __restrict__ b3,
    const float* __restrict__ nerf, const float* __restrict__ bw_in,
    float* __restrict__ out) {
    __shared__ float lds[64 * LSTRIDE];
    int tid = threadIdx.x;
    int p   = blockIdx.x * 64 + tid;

    // combine the 4 NN partials (ascending chunk order, strict < -> first min)
    float bd = nn_d2[p];
    int   bi = nn_ix[p];
#pragma unroll
    for (int c = 1; c < NCHUNK; ++c) {
        float d  = nn_d2[c * P_TOTAL + p];
        int   i2 = nn_ix[c * P_TOTAL + p];
        if (d < bd) { bd = d; bi = i2; }
    }

    // gather this point's feature row into its private LDS row
    const float4* fr = (const float4*)(tri_feats + (size_t)bi * NF);
    float* row = lds + tid * LSTRIDE;
#pragma unroll
    for (int i = 0; i < NF / 4; ++i) {
        float4 v = fr[i];
        row[4 * i + 0] = v.x; row[4 * i + 1] = v.y;
        row[4 * i + 2] = v.z; row[4 * i + 3] = v.w;
    }

    mlp_layer_full<NF>(row, W0, b0);   // 96 -> 128, relu (in-place)
    mlp_layer_full<NW>(row, W1, b1);   // 128 -> 128, relu (in-place)
    mlp_layer_full<NW>(row, W2, b2);   // 128 -> 128, relu (in-place)

    // final dot: 128 -> 1 (ascending-k fma chain)
    float acc = 0.0f;
#pragma unroll
    for (int k = 0; k < NW; ++k) acc = __fmaf_rn(row[k], W3[k], acc);
    float dens = __fadd_rn(acc, b3[0]);

    float xw = bw_in[0];
    float bw = 1.0f / (1.0f + expf(-xw));  // sigmoid (stop_gradient = identity fwd)
    float o  = __fadd_rn(__fmul_rn(bw, nerf[p]),
                         __fmul_rn(__fsub_rn(1.0f, bw), dens));
    out[p] = o;
}

extern "C" void kernel_launch(void* const* d_in, const int* in_sizes, int n_in,
                              void* d_out, int out_size, void* d_ws, size_t ws_size,
                              hipStream_t stream) {
    const float* pts   = (const float*)d_in[0];
    const float* verts = (const float*)d_in[1];
    const float* feats = (const float*)d_in[2];
    const float* nerf  = (const float*)d_in[3];
    const float* bw    = (const float*)d_in[4];
    const float* W0 = (const float*)d_in[5];
    const float* b0 = (const float*)d_in[6];
    const float* W1 = (const float*)d_in[7];
    const float* b1 = (const float*)d_in[8];
    const float* W2 = (const float*)d_in[9];
    const float* b2 = (const float*)d_in[10];
    const float* W3 = (const float*)d_in[11];
    const float* b3 = (const float*)d_in[12];

    char* ws = (char*)d_ws;
    float4* pts4  = (float4*)(ws);                              // 1 MB
    float4* vv    = (float4*)(ws + (1 << 20));                  // 110 KB
    float*  nn_d2 = (float*)(ws + (1 << 20) + (128 << 10));     // 1 MB
    int*    nn_ix = (int*)(ws + (2 << 20) + (128 << 10));       // 1 MB

    hipLaunchKernelGGL(k_norm, dim3(NRAYS), dim3(64), 0, stream, pts, pts4);
    hipLaunchKernelGGL(k_pack, dim3((NV + 255) / 256), dim3(256), 0, stream, verts, vv);
    hipLaunchKernelGGL(k_nn, dim3(P_TOTAL / 256, NCHUNK), dim3(256), 0, stream,
                       pts4, vv, nn_d2, nn_ix);
    hipLaunchKernelGGL(k_mlp, dim3(P_TOTAL / 64), dim3(64), 0, stream,
                       feats, nn_d2, nn_ix, W0, b0, W1, b1, W2, b2, W3, b3,
                       nerf, bw, (float*)d_out);
}

// Round 10
// 305.096 us; speedup vs baseline: 2.5274x; 1.9885x over previous
//
#include <hip/hip_runtime.h>
#include <math.h>

#define P_TOTAL 65536
#define NRAYS   1024
#define NSAMP   64
#define NV      6890
#define NF      96
#define NW      128
#define NCHUNK  4

// fused-MLP geometry
#define PTILE   32
#define THREADS 256
#define AS      132    // act row stride (words): 132%32=4 -> conflict-free a-reads; 16B-aligned rows
#define FS      100    // feats row stride (words): 400B rows, 16B-aligned
#define W_OFF   0      // [64][128] = 8192 floats max
#define H0_OFF  8192   // [32][132] = 4224 floats
#define H1_OFF  12416  // [32][132] = 4224 floats (layer-0 reads feats here with stride FS)
#define BI_OFF  16640  // 32 ints
#define LDS_FLOATS 16672  // 66,688 B -> 2 blocks/CU

// ---------------- K1: per-ray min/max normalize, pack (x,y,z,p2) ----------------
__global__ __launch_bounds__(64) void k_norm(const float* __restrict__ pts,
                                             float4* __restrict__ out) {
    int ray = blockIdx.x;
    int s   = threadIdx.x;
    const float* p = pts + (size_t)(ray * NSAMP + s) * 3;
    float x = p[0], y = p[1], z = p[2];
    float mnx = x, mxx = x, mny = y, mxy = y, mnz = z, mxz = z;
#pragma unroll
    for (int off = 32; off > 0; off >>= 1) {
        mnx = fminf(mnx, __shfl_xor(mnx, off));
        mxx = fmaxf(mxx, __shfl_xor(mxx, off));
        mny = fminf(mny, __shfl_xor(mny, off));
        mxy = fmaxf(mxy, __shfl_xor(mxy, off));
        mnz = fminf(mnz, __shfl_xor(mnz, off));
        mxz = fmaxf(mxz, __shfl_xor(mxz, off));
    }
    float nx = __fdiv_rn(__fsub_rn(x, mnx), __fsub_rn(mxx, mnx));
    float ny = __fdiv_rn(__fsub_rn(y, mny), __fsub_rn(mxy, mny));
    float nz = __fdiv_rn(__fsub_rn(z, mnz), __fsub_rn(mxz, mnz));
    float p2 = __fadd_rn(__fadd_rn(__fmul_rn(nx, nx), __fmul_rn(ny, ny)), __fmul_rn(nz, nz));
    out[ray * NSAMP + s] = make_float4(nx, ny, nz, p2);
}

// ---------------- K2: pack vertices as (x,y,z,v2) ----------------
__global__ __launch_bounds__(256) void k_pack(const float* __restrict__ verts,
                                              float4* __restrict__ vv) {
    int v = blockIdx.x * 256 + threadIdx.x;
    if (v < NV) {
        float x = verts[v * 3 + 0], y = verts[v * 3 + 1], z = verts[v * 3 + 2];
        float v2 = __fadd_rn(__fadd_rn(__fmul_rn(x, x), __fmul_rn(y, y)), __fmul_rn(z, z));
        vv[v] = make_float4(x, y, z, v2);
    }
}

// ---------------- K3: brute-force NN, vertex chunk staged in LDS ----------------
// LDS staging (27.6 KB) replaces serialized wave-uniform global loads: ds_read
// broadcast is prefetchable and the 5-blocks/CU occupancy (62%) gives TLP.
__global__ __launch_bounds__(256) void k_nn(const float4* __restrict__ pts,
                                            const float4* __restrict__ vv,
                                            float* __restrict__ nn_d2,
                                            int* __restrict__ nn_ix) {
    __shared__ float4 vlds[(NV + NCHUNK - 1) / NCHUNK + 1];
    int tid   = threadIdx.x;
    int chunk = blockIdx.y;
    int v0 = (chunk * NV) / NCHUNK;
    int v1 = ((chunk + 1) * NV) / NCHUNK;
    int cnt = v1 - v0;
    for (int i = tid; i < cnt; i += 256) vlds[i] = vv[v0 + i];
    __syncthreads();

    int p = blockIdx.x * 256 + tid;
    float4 pt = pts[p];
    float best = INFINITY;
    int bi = 0;
#pragma unroll 4
    for (int i = 0; i < cnt; ++i) {
        float4 vb = vlds[i];  // uniform addr -> conflict-free broadcast
        float dot = __fmaf_rn(pt.z, vb.z, __fmaf_rn(pt.y, vb.y, __fmul_rn(pt.x, vb.x)));
        float d2 = __fadd_rn(__fsub_rn(pt.w, __fmul_rn(2.0f, dot)), vb.w);
        if (d2 < best) { best = d2; bi = v0 + i; }  // strict < keeps FIRST min
    }
    nn_d2[chunk * P_TOTAL + p] = best;
    nn_ix[chunk * P_TOTAL + p] = bi;
}

// ---------------- one GEMM layer inside the fused kernel ----------------
// KTOT in {96,128}; W staged in K-halves into LDS (vector reads, not s_load).
// Each thread: 2 points x 8 cols = 16 independent FMAs per k-step.
// Accumulator carried across halves -> ascending-k sum order preserved exactly.
template <int KTOT, int ASTRIDE>
__device__ __forceinline__ void layer_run(float* lds, int aOff, int oOff,
                                          const float* __restrict__ Wg,
                                          const float* __restrict__ bg,
                                          int tid, int pl0, int pl1, int c8) {
    constexpr int KH = KTOT / 2;
    float acc0[8], acc1[8];
#pragma unroll
    for (int j = 0; j < 8; ++j) { acc0[j] = 0.0f; acc1[j] = 0.0f; }

#pragma unroll
    for (int h = 0; h < 2; ++h) {
        __syncthreads();  // all threads done with previous W contents / act writes
        {
            const float4* src = (const float4*)(Wg + (size_t)h * KH * NW);
            float4* wds = (float4*)(lds + W_OFF);
            for (int i = tid; i < KH * (NW / 4); i += THREADS) wds[i] = src[i];
        }
        __syncthreads();
        const float* arow0 = lds + aOff + pl0 * ASTRIDE + h * KH;
        const float* arow1 = lds + aOff + pl1 * ASTRIDE + h * KH;
#pragma unroll 4
        for (int k = 0; k < KH; ++k) {
            float a0 = arow0[k];
            float a1 = arow1[k];
            const float* wr = lds + W_OFF + k * NW + c8;
#pragma unroll
            for (int j = 0; j < 8; ++j) {
                float w = wr[j];
                acc0[j] = __fmaf_rn(a0, w, acc0[j]);
                acc1[j] = __fmaf_rn(a1, w, acc1[j]);
            }
        }
    }
    // epilogue: bias + relu -> act-out (distinct buffer from act-in: no barrier needed)
    float* o0 = lds + oOff + pl0 * AS + c8;
    float* o1 = lds + oOff + pl1 * AS + c8;
#pragma unroll
    for (int j = 0; j < 8; ++j) {
        float bb = bg[c8 + j];
        o0[j] = fmaxf(__fadd_rn(acc0[j], bb), 0.0f);
        o1[j] = fmaxf(__fadd_rn(acc1[j], bb), 0.0f);
    }
    __syncthreads();
}

// ---------------- K4: NN-combine + gather + 3-layer GEMM MLP + tail + blend ----------------
__global__ __launch_bounds__(THREADS, 2) void k_fused(
    const float* __restrict__ tri_feats,
    const float* __restrict__ nn_d2, const int* __restrict__ nn_ix,
    const float* __restrict__ W0, const float* __restrict__ b0,
    const float* __restrict__ W1, const float* __restrict__ b1,
    const float* __restrict__ W2, const float* __restrict__ b2,
    const float* __restrict__ W3, const float* __restrict__ b3,
    const float* __restrict__ nerf, const float* __restrict__ bw_in,
    float* __restrict__ out) {
    __shared__ __align__(16) float lds[LDS_FLOATS];
    int tid = threadIdx.x;
    int p0g = blockIdx.x * PTILE;

    // NN partial combine (ascending chunk order, strict < -> first min)
    if (tid < PTILE) {
        int pgl = p0g + tid;
        float bd = nn_d2[pgl];
        int   bi = nn_ix[pgl];
#pragma unroll
        for (int c = 1; c < NCHUNK; ++c) {
            float d  = nn_d2[c * P_TOTAL + pgl];
            int   i2 = nn_ix[c * P_TOTAL + pgl];
            if (d < bd) { bd = d; bi = i2; }
        }
        ((int*)(lds + BI_OFF))[tid] = bi;
    }
    __syncthreads();

    // gather feats rows into F (H1 region, stride FS) — 768 float4s, coalesced-ish
    for (int i = tid; i < PTILE * (NF / 4); i += THREADS) {
        int r  = i / (NF / 4);
        int c4 = i % (NF / 4);
        int bi = ((int*)(lds + BI_OFF))[r];
        float4 v = ((const float4*)(tri_feats + (size_t)bi * NF))[c4];
        *((float4*)(lds + H1_OFF + r * FS + c4 * 4)) = v;
    }

    int pg  = tid >> 4;
    int c8  = (tid & 15) * 8;
    int pl0 = pg * 2, pl1 = pg * 2 + 1;

    layer_run<NF, FS>(lds, H1_OFF, H0_OFF, W0, b0, tid, pl0, pl1, c8);  // 96 -> 128
    layer_run<NW, AS>(lds, H0_OFF, H1_OFF, W1, b1, tid, pl0, pl1, c8);  // 128 -> 128
    layer_run<NW, AS>(lds, H1_OFF, H0_OFF, W2, b2, tid, pl0, pl1, c8);  // 128 -> 128

    // tail: density = h . W3 + b3 (ascending-k), then blend
    if (tid < PTILE) {
        const float* hrow = lds + H0_OFF + tid * AS;
        float acc = 0.0f;
#pragma unroll 4
        for (int k = 0; k < NW; ++k) acc = __fmaf_rn(hrow[k], W3[k], acc);
        float dens = __fadd_rn(acc, b3[0]);
        int pgl = p0g + tid;
        float xw = bw_in[0];
        float bw = 1.0f / (1.0f + expf(-xw));  // sigmoid (stop_gradient = identity fwd)
        out[pgl] = __fadd_rn(__fmul_rn(bw, nerf[pgl]),
                             __fmul_rn(__fsub_rn(1.0f, bw), dens));
    }
}

extern "C" void kernel_launch(void* const* d_in, const int* in_sizes, int n_in,
                              void* d_out, int out_size, void* d_ws, size_t ws_size,
                              hipStream_t stream) {
    const float* pts   = (const float*)d_in[0];
    const float* verts = (const float*)d_in[1];
    const float* feats = (const float*)d_in[2];
    const float* nerf  = (const float*)d_in[3];
    const float* bw    = (const float*)d_in[4];
    const float* W0 = (const float*)d_in[5];
    const float* b0 = (const float*)d_in[6];
    const float* W1 = (const float*)d_in[7];
    const float* b1 = (const float*)d_in[8];
    const float* W2 = (const float*)d_in[9];
    const float* b2 = (const float*)d_in[10];
    const float* W3 = (const float*)d_in[11];
    const float* b3 = (const float*)d_in[12];

    char* ws = (char*)d_ws;
    float4* pts4  = (float4*)(ws);                              // 1 MB
    float4* vv    = (float4*)(ws + (1 << 20));                  // 110 KB
    float*  nn_d2 = (float*)(ws + (1 << 20) + (128 << 10));     // 1 MB
    int*    nn_ix = (int*)(ws + (2 << 20) + (128 << 10));       // 1 MB

    hipLaunchKernelGGL(k_norm, dim3(NRAYS), dim3(64), 0, stream, pts, pts4);
    hipLaunchKernelGGL(k_pack, dim3((NV + 255) / 256), dim3(256), 0, stream, verts, vv);
    hipLaunchKernelGGL(k_nn, dim3(P_TOTAL / 256, NCHUNK), dim3(256), 0, stream,
                       pts4, vv, nn_d2, nn_ix);
    hipLaunchKernelGGL(k_fused, dim3(P_TOTAL / PTILE), dim3(THREADS), 0, stream,
                       feats, nn_d2, nn_ix, W0, b0, W1, b1, W2, b2, W3, b3,
                       nerf, bw, (float*)d_out);
}

// Round 14
// 278.908 us; speedup vs baseline: 2.7648x; 1.0939x over previous
//
#include <hip/hip_runtime.h>
#include <math.h>

#define P_TOTAL 65536
#define NRAYS   1024
#define NSAMP   64
#define NV      6890
#define NF      96
#define NW      128
#define NCHUNK  4

// fused-MLP geometry
#define PTILE   32
#define THREADS 256
#define AS      132    // act row stride (words): 132%32=4 -> conflict-free a-reads; 16B-aligned rows
#define FS      100    // feats row stride (words): 400B rows, 16B-aligned
#define W_OFF   0      // [64][128] = 8192 floats max
#define H0_OFF  8192   // [32][132] = 4224 floats
#define H1_OFF  12416  // [32][132] = 4224 floats (layer-0 reads feats here with stride FS)
#define BI_OFF  16640  // 32 ints
#define LDS_FLOATS 16672  // 66,688 B -> 2 blocks/CU

// ---------------- K1: per-ray min/max normalize, pack (x,y,z,p2) ----------------
__global__ __launch_bounds__(64) void k_norm(const float* __restrict__ pts,
                                             float4* __restrict__ out) {
    int ray = blockIdx.x;
    int s   = threadIdx.x;
    const float* p = pts + (size_t)(ray * NSAMP + s) * 3;
    float x = p[0], y = p[1], z = p[2];
    float mnx = x, mxx = x, mny = y, mxy = y, mnz = z, mxz = z;
#pragma unroll
    for (int off = 32; off > 0; off >>= 1) {
        mnx = fminf(mnx, __shfl_xor(mnx, off));
        mxx = fmaxf(mxx, __shfl_xor(mxx, off));
        mny = fminf(mny, __shfl_xor(mny, off));
        mxy = fmaxf(mxy, __shfl_xor(mxy, off));
        mnz = fminf(mnz, __shfl_xor(mnz, off));
        mxz = fmaxf(mxz, __shfl_xor(mxz, off));
    }
    float nx = __fdiv_rn(__fsub_rn(x, mnx), __fsub_rn(mxx, mnx));
    float ny = __fdiv_rn(__fsub_rn(y, mny), __fsub_rn(mxy, mny));
    float nz = __fdiv_rn(__fsub_rn(z, mnz), __fsub_rn(mxz, mnz));
    float p2 = __fadd_rn(__fadd_rn(__fmul_rn(nx, nx), __fmul_rn(ny, ny)), __fmul_rn(nz, nz));
    out[ray * NSAMP + s] = make_float4(nx, ny, nz, p2);
}

// ---------------- K2: pack vertices as (x,y,z,v2) ----------------
__global__ __launch_bounds__(256) void k_pack(const float* __restrict__ verts,
                                              float4* __restrict__ vv) {
    int v = blockIdx.x * 256 + threadIdx.x;
    if (v < NV) {
        float x = verts[v * 3 + 0], y = verts[v * 3 + 1], z = verts[v * 3 + 2];
        float v2 = __fadd_rn(__fadd_rn(__fmul_rn(x, x), __fmul_rn(y, y)), __fmul_rn(z, z));
        vv[v] = make_float4(x, y, z, v2);
    }
}

// ---------------- K3: brute-force NN, vertex chunk staged in LDS ----------------
__global__ __launch_bounds__(256) void k_nn(const float4* __restrict__ pts,
                                            const float4* __restrict__ vv,
                                            float* __restrict__ nn_d2,
                                            int* __restrict__ nn_ix) {
    __shared__ float4 vlds[(NV + NCHUNK - 1) / NCHUNK + 1];
    int tid   = threadIdx.x;
    int chunk = blockIdx.y;
    int v0 = (chunk * NV) / NCHUNK;
    int v1 = ((chunk + 1) * NV) / NCHUNK;
    int cnt = v1 - v0;
    for (int i = tid; i < cnt; i += 256) vlds[i] = vv[v0 + i];
    __syncthreads();

    int p = blockIdx.x * 256 + tid;
    float4 pt = pts[p];
    float best = INFINITY;
    int bi = 0;
#pragma unroll 4
    for (int i = 0; i < cnt; ++i) {
        float4 vb = vlds[i];  // uniform addr -> conflict-free broadcast
        float dot = __fmaf_rn(pt.z, vb.z, __fmaf_rn(pt.y, vb.y, __fmul_rn(pt.x, vb.x)));
        // 2*dot is exact (exponent bump) -> fma(-2,dot,p2) == sub(p2, mul(2,dot)) bit-for-bit
        float d2 = __fadd_rn(__fmaf_rn(-2.0f, dot, pt.w), vb.w);
        if (d2 < best) { best = d2; bi = v0 + i; }  // strict < keeps FIRST min
    }
    nn_d2[chunk * P_TOTAL + p] = best;
    nn_ix[chunk * P_TOTAL + p] = bi;
}

// ---------------- one GEMM layer inside the fused kernel ----------------
// Column split {c4..c4+3, 64+c4..64+c4+3}: W ds_read_b128 lanes at word-stride 4
// -> banks 4m mod 32 -> 2 lanes/bank = 2-way alias (free, m136), vs 4-way at
// contiguous-8. Accumulator carried across K-halves -> ascending-k order exact.
template <int KTOT, int ASTRIDE>
__device__ __forceinline__ void layer_run(float* lds, int aOff, int oOff,
                                          const float* __restrict__ Wg,
                                          const float* __restrict__ bg,
                                          int tid, int pl0, int pl1, int c4) {
    constexpr int KH = KTOT / 2;
    float acc0a[4], acc0b[4], acc1a[4], acc1b[4];
#pragma unroll
    for (int j = 0; j < 4; ++j) { acc0a[j] = 0.0f; acc0b[j] = 0.0f; acc1a[j] = 0.0f; acc1b[j] = 0.0f; }

#pragma unroll
    for (int h = 0; h < 2; ++h) {
        __syncthreads();  // all threads done with previous W contents / act writes
        {
            const float4* src = (const float4*)(Wg + (size_t)h * KH * NW);
            float4* wds = (float4*)(lds + W_OFF);
            for (int i = tid; i < KH * (NW / 4); i += THREADS) wds[i] = src[i];
        }
        __syncthreads();
        const float* arow0 = lds + aOff + pl0 * ASTRIDE + h * KH;
        const float* arow1 = lds + aOff + pl1 * ASTRIDE + h * KH;
#pragma unroll 4
        for (int k = 0; k < KH; ++k) {
            float a0 = arow0[k];   // broadcast within 16-lane group
            float a1 = arow1[k];
            float4 wv0 = *(const float4*)(lds + W_OFF + k * NW + c4);        // 2-way
            float4 wv1 = *(const float4*)(lds + W_OFF + k * NW + 64 + c4);   // 2-way
            const float* w0 = (const float*)&wv0;
            const float* w1 = (const float*)&wv1;
#pragma unroll
            for (int j = 0; j < 4; ++j) {
                acc0a[j] = __fmaf_rn(a0, w0[j], acc0a[j]);
                acc1a[j] = __fmaf_rn(a1, w0[j], acc1a[j]);
                acc0b[j] = __fmaf_rn(a0, w1[j], acc0b[j]);
                acc1b[j] = __fmaf_rn(a1, w1[j], acc1b[j]);
            }
        }
    }
    // epilogue: bias + relu -> act-out (distinct buffer from act-in)
    float* o0 = lds + oOff + pl0 * AS;
    float* o1 = lds + oOff + pl1 * AS;
#pragma unroll
    for (int j = 0; j < 4; ++j) {
        float ba = bg[c4 + j];
        float bb = bg[64 + c4 + j];
        o0[c4 + j]      = fmaxf(__fadd_rn(acc0a[j], ba), 0.0f);
        o0[64 + c4 + j] = fmaxf(__fadd_rn(acc0b[j], bb), 0.0f);
        o1[c4 + j]      = fmaxf(__fadd_rn(acc1a[j], ba), 0.0f);
        o1[64 + c4 + j] = fmaxf(__fadd_rn(acc1b[j], bb), 0.0f);
    }
    __syncthreads();
}

// ---------------- K4: NN-combine + gather + 3-layer GEMM MLP + tail + blend ----------------
__global__ __launch_bounds__(THREADS, 2) void k_fused(
    const float* __restrict__ tri_feats,
    const float* __restrict__ nn_d2, const int* __restrict__ nn_ix,
    const float* __restrict__ W0, const float* __restrict__ b0,
    const float* __restrict__ W1, const float* __restrict__ b1,
    const float* __restrict__ W2, const float* __restrict__ b2,
    const float* __restrict__ W3, const float* __restrict__ b3,
    const float* __restrict__ nerf, const float* __restrict__ bw_in,
    float* __restrict__ out) {
    __shared__ __align__(16) float lds[LDS_FLOATS];
    int tid = threadIdx.x;
    int p0g = blockIdx.x * PTILE;

    // NN partial combine (ascending chunk order, strict < -> first min)
    if (tid < PTILE) {
        int pgl = p0g + tid;
        float bd = nn_d2[pgl];
        int   bi = nn_ix[pgl];
#pragma unroll
        for (int c = 1; c < NCHUNK; ++c) {
            float d  = nn_d2[c * P_TOTAL + pgl];
            int   i2 = nn_ix[c * P_TOTAL + pgl];
            if (d < bd) { bd = d; bi = i2; }
        }
        ((int*)(lds + BI_OFF))[tid] = bi;
    }
    __syncthreads();

    // gather feats rows into F (H1 region, stride FS)
    for (int i = tid; i < PTILE * (NF / 4); i += THREADS) {
        int r  = i / (NF / 4);
        int c4i = i % (NF / 4);
        int bi = ((int*)(lds + BI_OFF))[r];
        float4 v = ((const float4*)(tri_feats + (size_t)bi * NF))[c4i];
        *((float4*)(lds + H1_OFF + r * FS + c4i * 4)) = v;
    }

    int pg  = tid >> 4;
    int c4  = (tid & 15) * 4;
    int pl0 = pg * 2, pl1 = pg * 2 + 1;

    layer_run<NF, FS>(lds, H1_OFF, H0_OFF, W0, b0, tid, pl0, pl1, c4);  // 96 -> 128
    layer_run<NW, AS>(lds, H0_OFF, H1_OFF, W1, b1, tid, pl0, pl1, c4);  // 128 -> 128
    layer_run<NW, AS>(lds, H1_OFF, H0_OFF, W2, b2, tid, pl0, pl1, c4);  // 128 -> 128

    // tail: density = h . W3 + b3 (ascending-k), then blend
    if (tid < PTILE) {
        const float* hrow = lds + H0_OFF + tid * AS;
        float acc = 0.0f;
#pragma unroll 4
        for (int k = 0; k < NW; ++k) acc = __fmaf_rn(hrow[k], W3[k], acc);
        float dens = __fadd_rn(acc, b3[0]);
        int pgl = p0g + tid;
        float xw = bw_in[0];
        float bw = 1.0f / (1.0f + expf(-xw));  // sigmoid (stop_gradient = identity fwd)
        out[pgl] = __fadd_rn(__fmul_rn(bw, nerf[pgl]),
                             __fmul_rn(__fsub_rn(1.0f, bw), dens));
    }
}

extern "C" void kernel_launch(void* const* d_in, const int* in_sizes, int n_in,
                              void* d_out, int out_size, void* d_ws, size_t ws_size,
                              hipStream_t stream) {
    const float* pts   = (const float*)d_in[0];
    const float* verts = (const float*)d_in[1];
    const float* feats = (const float*)d_in[2];
    const float* nerf  = (const float*)d_in[3];
    const float* bw    = (const float*)d_in[4];
    const float* W0 = (const float*)d_in[5];
    const float* b0 = (const float*)d_in[6];
    const float* W1 = (const float*)d_in[7];
    const float* b1 = (const float*)d_in[8];
    const float* W2 = (const float*)d_in[9];
    const float* b2 = (const float*)d_in[10];
    const float* W3 = (const float*)d_in[11];
    const float* b3 = (const float*)d_in[12];

    char* ws = (char*)d_ws;
    float4* pts4  = (float4*)(ws);                              // 1 MB
    float4* vv    = (float4*)(ws + (1 << 20));                  // 110 KB
    float*  nn_d2 = (float*)(ws + (1 << 20) + (128 << 10));     // 1 MB
    int*    nn_ix = (int*)(ws + (2 << 20) + (128 << 10));       // 1 MB

    hipLaunchKernelGGL(k_norm, dim3(NRAYS), dim3(64), 0, stream, pts, pts4);
    hipLaunchKernelGGL(k_pack, dim3((NV + 255) / 256), dim3(256), 0, stream, verts, vv);
    hipLaunchKernelGGL(k_nn, dim3(P_TOTAL / 256, NCHUNK), dim3(256), 0, stream,
                       pts4, vv, nn_d2, nn_ix);
    hipLaunchKernelGGL(k_fused, dim3(P_TOTAL / PTILE), dim3(THREADS), 0, stream,
                       feats, nn_d2, nn_ix, W0, b0, W1, b1, W2, b2, W3, b3,
                       nerf, bw, (float*)d_out);
}